// Round 4
// baseline (139.985 us; speedup 1.0000x reference)
//
#include <hip/hip_runtime.h>
#include <stdint.h>

typedef __attribute__((ext_vector_type(8))) short short8;
typedef __attribute__((ext_vector_type(4))) short short4v;
typedef __attribute__((ext_vector_type(4))) float f32x4;
typedef __attribute__((ext_vector_type(2))) unsigned int uint2v;

#define S_LEN 4096
#define NBATCH 2
#define DMODEL 768
#define NH 12
#define HD 64
#define MROWS (S_LEN * NBATCH)   // 8192

__device__ __forceinline__ unsigned short f2bf(float f) {
    unsigned int u = __builtin_bit_cast(unsigned int, f);
    u += 0x7fffu + ((u >> 16) & 1u);       // round-to-nearest-even
    return (unsigned short)(u >> 16);
}

// async global->LDS, 16B per lane; LDS dst is wave-uniform base + lane*16,
// global src is PER-LANE (carries any layout permutation).
#define GLDS16(gp, lp) __builtin_amdgcn_global_load_lds( \
    (const __attribute__((address_space(1))) void*)(gp), \
    (__attribute__((address_space(3))) void*)(lp), 16, 0, 0)

// ---------------- kernel 1: val fp32 -> X bf16 (8192 x 768) ----------------
__global__ __launch_bounds__(256) void cvt_val_kernel(const float* __restrict__ in,
                                                      short* __restrict__ out) {
    size_t i = (size_t)blockIdx.x * 256 + threadIdx.x;
    const f32x4 v = *(const f32x4*)(in + i * 4);
    short4v o;
    o.x = (short)f2bf(v.x); o.y = (short)f2bf(v.y);
    o.z = (short)f2bf(v.z); o.w = (short)f2bf(v.w);
    *(short4v*)(out + i * 4) = o;
}

// ------------- kernel 2: W fp32 (K x N) -> WT bf16 (N x K), 3 weights -------------
__global__ __launch_bounds__(256) void cvt_w_kernel(const float* __restrict__ Wq,
                                                    const float* __restrict__ Wk,
                                                    const float* __restrict__ Wv,
                                                    short* __restrict__ WT) {
    const int z = blockIdx.z;
    const float* W = (z == 0) ? Wq : ((z == 1) ? Wk : Wv);
    const int n  = blockIdx.x * 256 + threadIdx.x;
    const int k0 = blockIdx.y * 8;
    short8 o;
#pragma unroll
    for (int i = 0; i < 8; ++i)
        o[i] = (short)f2bf(W[(size_t)(k0 + i) * DMODEL + n]);
    *(short8*)(WT + (size_t)z * DMODEL * DMODEL + (size_t)n * DMODEL + k0) = o;
}

// ------- kernel 3: QKV GEMM, 128x128 tile, BK=32 -------
// A: glds-staged, kg-major LDS layout (conflict-free frag reads), 3-deep
// counted-vmcnt pipeline. B: direct from global (L2-resident W after XCD
// swizzle), register-prefetched 1 step ahead. 1-D grid, XCD-chunked.
#define NT 24   // 768/32 K-steps
__global__ __launch_bounds__(256, 4) void gemm_qkv_kernel(
    const short* __restrict__ X, const short* __restrict__ WT,
    const float* __restrict__ bq, const float* __restrict__ bk, const float* __restrict__ bv,
    short* __restrict__ Q, short* __restrict__ K, short* __restrict__ V)
{
    __shared__ __align__(16) short SMEM[17408];   // A stage 3*4096 shorts; reused as C[128][136]
    short* As = SMEM;

    const int phys = blockIdx.x;                       // 1152 blocks = 8 XCD * 144
    const int logical = (phys & 7) * 144 + (phys >> 3);  // bijective XCD chunking
    const int xb = logical % 6;                        // n-block (shares A-panel across xb)
    const int yb = (logical / 6) & 63;                 // m-block
    const int z  = logical / 384;                      // weight index
    const int n0 = xb * 128;
    const int m0 = yb * 128;

    const int tid = threadIdx.x, lane = tid & 63, wid = tid >> 6;
    const short* W    = WT + (size_t)z * DMODEL * DMODEL;
    const float* bias = (z == 0) ? bq : ((z == 1) ? bk : bv);
    short*       OUT  = (z == 0) ? Q  : ((z == 1) ? K  : V);

    const f32x4 zero4 = {0.f, 0.f, 0.f, 0.f};
    f32x4 acc[4][4];
#pragma unroll
    for (int i = 0; i < 4; ++i)
#pragma unroll
        for (int j = 0; j < 4; ++j) acc[i][j] = zero4;

    const int fr = lane & 15, kg = lane >> 4;
    const int wr = (wid >> 1) * 64, wc = (wid & 1) * 64;

    // A staging: LDS unit(kg,row) at shorts kg*1024 + row*8. Wave wid stages
    // kg=wid; lane l covers row 64j+l. Global src per-lane carries the permutation.
    const short* gA = X + (size_t)(m0 + lane) * DMODEL + wid * 8;
#define STAGEA(buf, kt) do { \
        GLDS16(gA + (kt),               As + (buf) * 4096 + wid * 1024);       \
        GLDS16(gA + (kt) + 64 * DMODEL, As + (buf) * 4096 + wid * 1024 + 512); \
    } while (0)

    // B fragment base: row n0+wc+ni*16+fr, cols kt + kg*8
    const short* gB = W + (size_t)(n0 + wc + fr) * DMODEL + kg * 8;

    short8 bc[4], bn[4];
#pragma unroll
    for (int ni = 0; ni < 4; ++ni)
        bc[ni] = *(const short8*)(gB + ni * 16 * DMODEL);      // B(0), oldest in queue
    __builtin_amdgcn_sched_barrier(0);
    STAGEA(0, 0);
    STAGEA(1, 32);
    __builtin_amdgcn_sched_barrier(0);
    // queue: [B0(4), A0(2), A1(2)] -> steady-state wait leaves 2 newest (next A tile)

    for (int t = 0; t < NT; ++t) {
        if (t < NT - 1) { asm volatile("s_waitcnt vmcnt(2)" ::: "memory"); }
        else            { asm volatile("s_waitcnt vmcnt(0)" ::: "memory"); }
        __builtin_amdgcn_sched_barrier(0);
        __builtin_amdgcn_s_barrier();           // tile t in LDS for all waves
        __builtin_amdgcn_sched_barrier(0);

        if (t + 1 < NT) {                       // issue B(t+1) BEFORE A(t+2): queue order
            const short* gBn = gB + (t + 1) * 32;
#pragma unroll
            for (int ni = 0; ni < 4; ++ni)
                bn[ni] = *(const short8*)(gBn + ni * 16 * DMODEL);
        }
        __builtin_amdgcn_sched_barrier(0);
        if (t + 2 < NT) STAGEA((t + 2) % 3, (t + 2) * 32);
        __builtin_amdgcn_sched_barrier(0);

        const short* Ab = As + (t % 3) * 4096 + kg * 1024;
        short8 af[4];
#pragma unroll
        for (int mi = 0; mi < 4; ++mi)
            af[mi] = *(const short8*)(Ab + (wr + mi * 16 + fr) * 8);

        __builtin_amdgcn_s_setprio(1);
#pragma unroll
        for (int mi = 0; mi < 4; ++mi)
#pragma unroll
            for (int ni = 0; ni < 4; ++ni)
                acc[mi][ni] = __builtin_amdgcn_mfma_f32_16x16x32_bf16(
                    af[mi], bc[ni], acc[mi][ni], 0, 0, 0);
        __builtin_amdgcn_s_setprio(0);

        if (t + 1 < NT) {
#pragma unroll
            for (int ni = 0; ni < 4; ++ni) bc[ni] = bn[ni];
        }
    }
#undef STAGEA

    __syncthreads();                        // staging LDS dead; repurpose for C tile
    const float scale = (z == 0) ? 0.125f : 1.0f;   // q /= sqrt(64)
    float bval[4];
#pragma unroll
    for (int ni = 0; ni < 4; ++ni) bval[ni] = bias[n0 + wc + ni * 16 + fr];

    short* Cs = SMEM;                       // [128][136] bf16
#pragma unroll
    for (int mi = 0; mi < 4; ++mi)
#pragma unroll
        for (int ni = 0; ni < 4; ++ni)
#pragma unroll
            for (int r = 0; r < 4; ++r)
                Cs[(wr + mi * 16 + 4 * kg + r) * 136 + (wc + ni * 16 + fr)] =
                    (short)f2bf((acc[mi][ni][r] + bval[ni]) * scale);
    __syncthreads();

#pragma unroll
    for (int i = 0; i < 8; ++i) {           // 2048 chunks of 8 elems, coalesced
        const int flat = i * 256 + tid;
        const int row = flat >> 4, c8 = (flat & 15) * 8;
        const int gm = m0 + row, gn = n0 + c8;
        const int s = gm >> 1, bb = gm & 1, hh = gn >> 6, e0 = gn & 63;
        *(short8*)(&OUT[((size_t)(bb * NH + hh) * S_LEN + s) * HD + e0]) =
            *(const short8*)(&Cs[row * 136 + c8]);
    }
}

// ---------------- kernel 4: V [bh][s][e] -> Vt [bh][e][s] ----------------
__global__ __launch_bounds__(256) void transpose_v_kernel(const short* __restrict__ V,
                                                          short* __restrict__ Vt) {
    __shared__ __align__(16) short T[64][72];
    const int bh = blockIdx.x;
    const int s0 = blockIdx.y * 64;
    const int t  = threadIdx.x;
    const short* Vb  = V  + (size_t)bh * S_LEN * HD;
    short*       Vtb = Vt + (size_t)bh * HD * S_LEN;

    const int sl = t >> 3, e0 = (t & 7) * 8;
#pragma unroll
    for (int i = 0; i < 2; ++i) {
        short8 v = *(const short8*)(Vb + (size_t)(s0 + sl + i * 32) * HD + e0);
        *(short8*)(&T[sl + i * 32][e0]) = v;
    }
    __syncthreads();
    const int e  = t & 63;
    const int sb = (t >> 6) * 16;
    short vv[16];
#pragma unroll
    for (int j = 0; j < 16; ++j) vv[j] = T[sb + j][e];
    short8 a, b;
#pragma unroll
    for (int j = 0; j < 8; ++j) { a[j] = vv[j]; b[j] = vv[8 + j]; }
    *(short8*)(Vtb + (size_t)e * S_LEN + s0 + sb)     = a;
    *(short8*)(Vtb + (size_t)e * S_LEN + s0 + sb + 8) = b;
}

// ---------------- kernel 5: banded causal attention, 8 waves x 16 queries ----------------
#define QB   128
#define KWIN 384
#define KST  72     // K LDS row stride (elems): 144B -> 4-bank rotation per row
#define VST  392    // Vt LDS row stride: 784B -> 4-bank rotation per row
#define PCST 40     // P chunk buffer row stride (80B, 16B-aligned rows)

__global__ __launch_bounds__(512, 2) void attn_kernel(
    const short* __restrict__ Q, const short* __restrict__ K,
    const short* __restrict__ Vt, float* __restrict__ out)
{
    __shared__ __align__(16) short Ks[KWIN * KST];        // 55296 B
    __shared__ __align__(16) short Vs[HD * VST];          // 50176 B
    __shared__ __align__(16) short Pc[8][2][16 * PCST];   // 20480 B  (per-wave ping-pong)

    const int tid = threadIdx.x, lane = tid & 63, wid = tid >> 6;
    const int q0 = blockIdx.x * QB;
    const int bh = blockIdx.y;
    const int bb = bh / NH, hh = bh % NH;
    const int fr = lane & 15, g = lane >> 4;
    const int kstart = q0 - 256;

    const short* Qb = Q  + (size_t)bh * S_LEN * HD;
    const short* Kb = K  + (size_t)bh * S_LEN * HD;
    const short* Vb = Vt + (size_t)bh * HD * S_LEN;

    // ---- cooperative staging (coalesced 16B segments) ----
#pragma unroll
    for (int it = 0; it < 6; ++it) {                 // K: 384 rows x 64 elems
        const int seg = it * 512 + tid;
        const int row = seg >> 3, c8 = (seg & 7) * 8;
        int sr = kstart + row; sr = sr < 0 ? 0 : sr;  // garbage rows masked later
        *(short8*)(Ks + row * KST + c8) = *(const short8*)(Kb + (size_t)sr * HD + c8);
    }
#pragma unroll
    for (int it = 0; it < 6; ++it) {                 // Vt: 64 rows x 384 key-cols
        const int seg = it * 512 + tid;
        const int row = seg / 48, cc = seg % 48;
        int sk = kstart + cc * 8; sk = sk < 0 ? 0 : sk;
        *(short8*)(Vs + row * VST + cc * 8) = *(const short8*)(Vb + (size_t)row * S_LEN + sk);
    }
    __syncthreads();

    // ---- Q fragments (B-operand: col=query=fr, k=8g+i) ----
    const int qrow = q0 + wid * 16 + fr;
    const short8 qa0 = *(const short8*)(Qb + (size_t)qrow * HD + g * 8);
    const short8 qa1 = *(const short8*)(Qb + (size_t)qrow * HD + 32 + g * 8);

    // ---- QK^T: 17 tiles ----
    float sc[17][4];
#pragma unroll
    for (int t = 0; t < 17; ++t) {
        const short* kr = Ks + ((wid + t) * 16 + fr) * KST;   // A row = key
        const short8 a0 = *(const short8*)(kr + g * 8);
        const short8 a1 = *(const short8*)(kr + 32 + g * 8);
        f32x4 d = {0.f, 0.f, 0.f, 0.f};
        d = __builtin_amdgcn_mfma_f32_16x16x32_bf16(a0, qa0, d, 0, 0, 0);
        d = __builtin_amdgcn_mfma_f32_16x16x32_bf16(a1, qa1, d, 0, 0, 0);
        const int gk0 = kstart + (wid + t) * 16 + 4 * g;      // global key (+r)
#pragma unroll
        for (int r = 0; r < 4; ++r) {
            const int dd = 256 + fr - 16 * t - 4 * g - r;     // query - key
            const bool ok = (dd >= 0) & (dd <= 256) & (gk0 + r >= 0);
            sc[t][r] = ok ? d[r] : -1e30f;
        }
    }

    // ---- softmax max (row = query = fr; reduce across g-groups) ----
    float mx = -1e30f;
#pragma unroll
    for (int t = 0; t < 17; ++t)
#pragma unroll
        for (int r = 0; r < 4; ++r) mx = fmaxf(mx, sc[t][r]);
    mx = fmaxf(mx, __shfl_xor(mx, 16));
    mx = fmaxf(mx, __shfl_xor(mx, 32));

    // ---- chunked exp + P redistribute (per-wave LDS, no barrier) + PV ----
    float sm = 0.f;
    f32x4 o[4];
#pragma unroll
    for (int et = 0; et < 4; ++et) o[et] = (f32x4){0.f, 0.f, 0.f, 0.f};

#pragma unroll
    for (int c = 0; c < 9; ++c) {
        float pv[8];
#pragma unroll
        for (int j = 0; j < 8; ++j) {
            const int t = 2 * c + (j >> 2);
            pv[j] = (t < 17) ? __expf(sc[t][j & 3] - mx) : 0.f;   // masked -> exp(-1e30)=0
            sm += pv[j];
        }
        unsigned int u0 = (unsigned)f2bf(pv[0]) | ((unsigned)f2bf(pv[1]) << 16);
        unsigned int u1 = (unsigned)f2bf(pv[2]) | ((unsigned)f2bf(pv[3]) << 16);
        unsigned int u2 = (unsigned)f2bf(pv[4]) | ((unsigned)f2bf(pv[5]) << 16);
        unsigned int u3 = (unsigned)f2bf(pv[6]) | ((unsigned)f2bf(pv[7]) << 16);
        short* pb = &Pc[wid][c & 1][0];
        *(uint2v*)(pb + fr * PCST + 4 * g)      = (uint2v){u0, u1};  // keys 4g..4g+3 (tile 2c)
        *(uint2v*)(pb + fr * PCST + 16 + 4 * g) = (uint2v){u2, u3};  // keys 16+4g..  (tile 2c+1)
        const short8 pa = *(const short8*)(pb + fr * PCST + 8 * g);  // A-frag: q=fr, k=8g..
        int ka = wid * 16 + 32 * c + 8 * g;
        ka = ka > KWIN - 8 ? KWIN - 8 : ka;        // clamped lanes have P=0
#pragma unroll
        for (int et = 0; et < 4; ++et) {
            const short8 vb = *(const short8*)(Vs + (et * 16 + fr) * VST + ka);
            o[et] = __builtin_amdgcn_mfma_f32_16x16x32_bf16(pa, vb, o[et], 0, 0, 0);
        }
    }

    sm += __shfl_xor(sm, 16);
    sm += __shfl_xor(sm, 32);
    const float inv = 1.0f / sm;                   // valid for query = fr
    float inv4[4];
#pragma unroll
    for (int r = 0; r < 4; ++r) inv4[r] = __shfl(inv, 4 * g + r);   // PV D-row = query 4g+r

#pragma unroll
    for (int et = 0; et < 4; ++et)
#pragma unroll
        for (int r = 0; r < 4; ++r) {
            const int qi = q0 + wid * 16 + 4 * g + r;
            const int dd = hh * HD + et * 16 + fr;
            out[((size_t)qi * NBATCH + bb) * DMODEL + dd] = o[et][r] * inv4[r];
        }
}

extern "C" void kernel_launch(void* const* d_in, const int* in_sizes, int n_in,
                              void* d_out, int out_size, void* d_ws, size_t ws_size,
                              hipStream_t stream) {
    (void)in_sizes; (void)n_in; (void)out_size; (void)ws_size;
    const float* val = (const float*)d_in[0];
    const float* Wq  = (const float*)d_in[1];
    const float* bq  = (const float*)d_in[2];
    const float* Wk  = (const float*)d_in[3];
    const float* bk  = (const float*)d_in[4];
    const float* Wv  = (const float*)d_in[5];
    const float* bv  = (const float*)d_in[6];
    float* out = (float*)d_out;

    char* ws = (char*)d_ws;
    const size_t SZ_X  = (size_t)MROWS * DMODEL * 2;
    const size_t SZ_W  = (size_t)DMODEL * DMODEL * 2;
    short* X  = (short*)(ws);
    short* WT = (short*)(ws + SZ_X);
    short* Qb = (short*)(ws + SZ_X + 3 * SZ_W);
    short* Kb = (short*)(ws + SZ_X + 3 * SZ_W + SZ_X);
    short* Vb = (short*)(ws + SZ_X + 3 * SZ_W + 2 * SZ_X);
    short* Vt = (short*)(ws + SZ_X + 3 * SZ_W + 3 * SZ_X);

    cvt_val_kernel<<<dim3((MROWS * DMODEL) / 4 / 256), dim3(256), 0, stream>>>(val, X);
    cvt_w_kernel<<<dim3(3, 96, 3), dim3(256), 0, stream>>>(Wq, Wk, Wv, WT);
    gemm_qkv_kernel<<<dim3(1152), dim3(256), 0, stream>>>(
        X, WT, bq, bk, bv, Qb, Kb, Vb);
    transpose_v_kernel<<<dim3(NBATCH * NH, S_LEN / 64), dim3(256), 0, stream>>>(Vb, Vt);
    attn_kernel<<<dim3(S_LEN / QB, NBATCH * NH), dim3(512), 0, stream>>>(Qb, Kb, Vt, out);
}

// Round 5
// 93.773 us; speedup vs baseline: 1.4928x; 1.4928x over previous
//
#include <hip/hip_runtime.h>
#include <stdint.h>

typedef __attribute__((ext_vector_type(8))) short short8;
typedef __attribute__((ext_vector_type(4))) short short4v;
typedef __attribute__((ext_vector_type(4))) float f32x4;
typedef __attribute__((ext_vector_type(2))) unsigned int uint2v;

#define S_LEN 4096
#define NBATCH 2
#define DMODEL 768
#define NH 12
#define HD 64
#define MROWS (S_LEN * NBATCH)   // 8192
#define NFUSED 2304              // 3 * DMODEL

__device__ __forceinline__ unsigned short f2bf(float f) {
    unsigned int u = __builtin_bit_cast(unsigned int, f);
    u += 0x7fffu + ((u >> 16) & 1u);       // round-to-nearest-even
    return (unsigned short)(u >> 16);
}

// async global->LDS, 16B per lane; LDS dst = wave-uniform base + lane*16,
// global src is PER-LANE (carries the within-row slot permutation).
#define GLDS16(gp, lp) __builtin_amdgcn_global_load_lds( \
    (const __attribute__((address_space(1))) void*)(gp), \
    (__attribute__((address_space(3))) void*)(lp), 16, 0, 0)

// ---------------- kernel 1: val fp32 -> X bf16 (8192 x 768) ----------------
__global__ __launch_bounds__(256) void cvt_val_kernel(const float* __restrict__ in,
                                                      short* __restrict__ out) {
    size_t i = (size_t)blockIdx.x * 256 + threadIdx.x;
    const f32x4 v = *(const f32x4*)(in + i * 4);
    short4v o;
    o.x = (short)f2bf(v.x); o.y = (short)f2bf(v.y);
    o.z = (short)f2bf(v.z); o.w = (short)f2bf(v.w);
    *(short4v*)(out + i * 4) = o;
}

// --- kernel 2: W fp32 (K x N) -> WT bf16 fused (nf x K), nf = z*768 + n ---
__global__ __launch_bounds__(256) void cvt_w_kernel(const float* __restrict__ Wq,
                                                    const float* __restrict__ Wk,
                                                    const float* __restrict__ Wv,
                                                    short* __restrict__ WT) {
    const int z = blockIdx.z;
    const float* W = (z == 0) ? Wq : ((z == 1) ? Wk : Wv);
    const int n  = blockIdx.x * 256 + threadIdx.x;
    const int k0 = blockIdx.y * 8;
    short8 o;
#pragma unroll
    for (int i = 0; i < 8; ++i)
        o[i] = (short)f2bf(W[(size_t)(k0 + i) * DMODEL + n]);
    *(short8*)(WT + (size_t)z * DMODEL * DMODEL + (size_t)n * DMODEL + k0) = o;
}

// ------- kernel 3: fused QKV GEMM  C[8192 x 2304] = X * WT^T -------
// 128x128 tile, BK=32, coalesced glds staging (64B segments), 3-deep
// counted-vmcnt pipeline, rule-21 slot swizzle (global src permuted within
// row; swizzled ds_read -> 2-way banks). XCD m-chunked block order.
#define NT 24   // 768/32 K-steps
__global__ __launch_bounds__(256) void gemm_qkv_kernel(
    const short* __restrict__ X, const short* __restrict__ WT,
    const float* __restrict__ bq, const float* __restrict__ bk, const float* __restrict__ bv,
    short* __restrict__ Q, short* __restrict__ K, short* __restrict__ V)
{
    __shared__ __align__(16) short SMEM[24576];   // 48 KB: A[3][4096] | B[3][4096]; reused for C
    short* As = SMEM;
    short* Bs = SMEM + 12288;

    // 1152 blocks = 8 XCD x (8 m-panels x 18 n-blocks), n-fastest in XCD
    const int phys = blockIdx.x;
    const int xcd = phys & 7, i = phys >> 3;
    const int m0 = (xcd * 8 + i / 18) * 128;
    const int n0 = (i % 18) * 128;                 // fused-N coordinate
    const int z  = n0 / DMODEL;                    // weight id (128 | 768)
    const int n0w = n0 - z * DMODEL;

    const int tid = threadIdx.x, lane = tid & 63, wid = tid >> 6;
    const float* bias = (z == 0) ? bq : ((z == 1) ? bk : bv);
    short*       OUT  = (z == 0) ? Q  : ((z == 1) ? K  : V);

    const f32x4 zero4 = {0.f, 0.f, 0.f, 0.f};
    f32x4 acc[4][4];
#pragma unroll
    for (int i2 = 0; i2 < 4; ++i2)
#pragma unroll
        for (int j = 0; j < 4; ++j) acc[i2][j] = zero4;

    const int fr = lane & 15, kg = lane >> 4;
    const int wr = (wid >> 1) * 64, wc = (wid & 1) * 64;

    // staging: wave wid covers rows [wid*32, wid*32+32); lane -> row=l>>2,
    // slot=(l&3). Source slot permuted within the row: gslot = (l&3)^((l>>3)&3)
    // (row bits 1-2 = (l>>2)&3 >>1 = (l>>3)&3). Same 64B segment -> coalesced.
    const int gslot = (lane & 3) ^ ((lane >> 3) & 3);
    const short* gA = X  + (size_t)(m0 + wid * 32 + (lane >> 2)) * DMODEL + gslot * 8;
    const short* gB = WT + (size_t)(n0 + wid * 32 + (lane >> 2)) * DMODEL + gslot * 8;

#define STAGE(buf, kt) do { \
        GLDS16(gA + (kt),               As + (buf) * 4096 + wid * 1024);        \
        GLDS16(gA + (kt) + 16 * DMODEL, As + (buf) * 4096 + wid * 1024 + 512);  \
        GLDS16(gB + (kt),               Bs + (buf) * 4096 + wid * 1024);        \
        GLDS16(gB + (kt) + 16 * DMODEL, Bs + (buf) * 4096 + wid * 1024 + 512);  \
    } while (0)

    STAGE(0, 0);
    STAGE(1, 32);
    // fragment read slot: kg ^ ((row>>1)&3); row bits 1-2 come from fr
    const int rslot = ((fr >> 1) & 3);
    for (int t = 0; t < NT; ++t) {
        if (t + 2 < NT) { asm volatile("s_waitcnt vmcnt(4)" ::: "memory"); }
        else            { asm volatile("s_waitcnt vmcnt(0)" ::: "memory"); }
        __builtin_amdgcn_sched_barrier(0);
        __builtin_amdgcn_s_barrier();      // tile t fully in LDS for all waves
        __builtin_amdgcn_sched_barrier(0);
        if (t + 2 < NT) STAGE((t + 2) % 3, (t + 2) * 32);   // WAR-safe post-barrier

        const short* Ab = As + (t % 3) * 4096;
        const short* Bb = Bs + (t % 3) * 4096;
        short8 af[4], bfv[4];
#pragma unroll
        for (int mi = 0; mi < 4; ++mi)
            af[mi] = *(const short8*)(Ab + (wr + mi * 16 + fr) * 32 + (kg ^ rslot) * 8);
#pragma unroll
        for (int ni = 0; ni < 4; ++ni)
            bfv[ni] = *(const short8*)(Bb + (wc + ni * 16 + fr) * 32 + (kg ^ rslot) * 8);
        __builtin_amdgcn_s_setprio(1);
#pragma unroll
        for (int mi = 0; mi < 4; ++mi)
#pragma unroll
            for (int ni = 0; ni < 4; ++ni)
                acc[mi][ni] = __builtin_amdgcn_mfma_f32_16x16x32_bf16(
                    af[mi], bfv[ni], acc[mi][ni], 0, 0, 0);
        __builtin_amdgcn_s_setprio(0);
    }
#undef STAGE

    __syncthreads();                        // staging LDS dead; repurpose for C tile
    const float scale = (z == 0) ? 0.125f : 1.0f;   // q /= sqrt(64)
    float bval[4];
#pragma unroll
    for (int ni = 0; ni < 4; ++ni) bval[ni] = bias[n0w + wc + ni * 16 + fr];

    short* Cs = SMEM;                       // [128][136] bf16
#pragma unroll
    for (int mi = 0; mi < 4; ++mi)
#pragma unroll
        for (int ni = 0; ni < 4; ++ni)
#pragma unroll
            for (int r = 0; r < 4; ++r)
                Cs[(wr + mi * 16 + 4 * kg + r) * 136 + (wc + ni * 16 + fr)] =
                    (short)f2bf((acc[mi][ni][r] + bval[ni]) * scale);
    __syncthreads();

#pragma unroll
    for (int i2 = 0; i2 < 8; ++i2) {        // 2048 chunks of 8 elems, coalesced
        const int flat = i2 * 256 + tid;
        const int row = flat >> 4, c8 = (flat & 15) * 8;
        const int gm = m0 + row, gn = n0w + c8;
        const int s = gm >> 1, bb = gm & 1, hh = gn >> 6, e0 = gn & 63;
        *(short8*)(&OUT[((size_t)(bb * NH + hh) * S_LEN + s) * HD + e0]) =
            *(const short8*)(&Cs[row * 136 + c8]);
    }
}

// ---------------- kernel 4: V [bh][s][e] -> Vt [bh][e][s] ----------------
__global__ __launch_bounds__(256) void transpose_v_kernel(const short* __restrict__ V,
                                                          short* __restrict__ Vt) {
    __shared__ __align__(16) short T[64][72];
    const int bh = blockIdx.x;
    const int s0 = blockIdx.y * 64;
    const int t  = threadIdx.x;
    const short* Vb  = V  + (size_t)bh * S_LEN * HD;
    short*       Vtb = Vt + (size_t)bh * HD * S_LEN;

    const int sl = t >> 3, e0 = (t & 7) * 8;
#pragma unroll
    for (int i = 0; i < 2; ++i) {
        short8 v = *(const short8*)(Vb + (size_t)(s0 + sl + i * 32) * HD + e0);
        *(short8*)(&T[sl + i * 32][e0]) = v;
    }
    __syncthreads();
    const int e  = t & 63;
    const int sb = (t >> 6) * 16;
    short vv[16];
#pragma unroll
    for (int j = 0; j < 16; ++j) vv[j] = T[sb + j][e];
    short8 a, b;
#pragma unroll
    for (int j = 0; j < 8; ++j) { a[j] = vv[j]; b[j] = vv[8 + j]; }
    *(short8*)(Vtb + (size_t)e * S_LEN + s0 + sb)     = a;
    *(short8*)(Vtb + (size_t)e * S_LEN + s0 + sb + 8) = b;
}

// ---------------- kernel 5: banded causal attention, 8 waves x 16 queries ----------------
#define QB   128
#define KWIN 384
#define KST  72     // K LDS row stride (elems): 144B -> 4-bank rotation per row
#define VST  392    // Vt LDS row stride: 784B -> 4-bank rotation per row
#define PCST 40     // P chunk buffer row stride (80B, 16B-aligned rows)

__global__ __launch_bounds__(512, 2) void attn_kernel(
    const short* __restrict__ Q, const short* __restrict__ K,
    const short* __restrict__ Vt, float* __restrict__ out)
{
    __shared__ __align__(16) short Ks[KWIN * KST];        // 55296 B
    __shared__ __align__(16) short Vs[HD * VST];          // 50176 B
    __shared__ __align__(16) short Pc[8][2][16 * PCST];   // 20480 B  (per-wave ping-pong)

    const int tid = threadIdx.x, lane = tid & 63, wid = tid >> 6;
    const int q0 = blockIdx.x * QB;
    const int bh = blockIdx.y;
    const int bb = bh / NH, hh = bh % NH;
    const int fr = lane & 15, g = lane >> 4;
    const int kstart = q0 - 256;

    const short* Qb = Q  + (size_t)bh * S_LEN * HD;
    const short* Kb = K  + (size_t)bh * S_LEN * HD;
    const short* Vb = Vt + (size_t)bh * HD * S_LEN;

    // ---- cooperative staging (coalesced 16B segments) ----
#pragma unroll
    for (int it = 0; it < 6; ++it) {                 // K: 384 rows x 64 elems
        const int seg = it * 512 + tid;
        const int row = seg >> 3, c8 = (seg & 7) * 8;
        int sr = kstart + row; sr = sr < 0 ? 0 : sr;  // garbage rows masked later
        *(short8*)(Ks + row * KST + c8) = *(const short8*)(Kb + (size_t)sr * HD + c8);
    }
#pragma unroll
    for (int it = 0; it < 6; ++it) {                 // Vt: 64 rows x 384 key-cols
        const int seg = it * 512 + tid;
        const int row = seg / 48, cc = seg % 48;
        int sk = kstart + cc * 8; sk = sk < 0 ? 0 : sk;
        *(short8*)(Vs + row * VST + cc * 8) = *(const short8*)(Vb + (size_t)row * S_LEN + sk);
    }
    __syncthreads();

    // ---- Q fragments (B-operand: col=query=fr, k=8g+i) ----
    const int qrow = q0 + wid * 16 + fr;
    const short8 qa0 = *(const short8*)(Qb + (size_t)qrow * HD + g * 8);
    const short8 qa1 = *(const short8*)(Qb + (size_t)qrow * HD + 32 + g * 8);

    // ---- QK^T: 17 tiles ----
    float sc[17][4];
#pragma unroll
    for (int t = 0; t < 17; ++t) {
        const short* kr = Ks + ((wid + t) * 16 + fr) * KST;   // A row = key
        const short8 a0 = *(const short8*)(kr + g * 8);
        const short8 a1 = *(const short8*)(kr + 32 + g * 8);
        f32x4 d = {0.f, 0.f, 0.f, 0.f};
        d = __builtin_amdgcn_mfma_f32_16x16x32_bf16(a0, qa0, d, 0, 0, 0);
        d = __builtin_amdgcn_mfma_f32_16x16x32_bf16(a1, qa1, d, 0, 0, 0);
        const int gk0 = kstart + (wid + t) * 16 + 4 * g;      // global key (+r)
#pragma unroll
        for (int r = 0; r < 4; ++r) {
            const int dd = 256 + fr - 16 * t - 4 * g - r;     // query - key
            const bool ok = (dd >= 0) & (dd <= 256) & (gk0 + r >= 0);
            sc[t][r] = ok ? d[r] : -1e30f;
        }
    }

    // ---- softmax max (row = query = fr; reduce across g-groups) ----
    float mx = -1e30f;
#pragma unroll
    for (int t = 0; t < 17; ++t)
#pragma unroll
        for (int r = 0; r < 4; ++r) mx = fmaxf(mx, sc[t][r]);
    mx = fmaxf(mx, __shfl_xor(mx, 16));
    mx = fmaxf(mx, __shfl_xor(mx, 32));

    // ---- chunked exp + P redistribute (per-wave LDS, no barrier) + PV ----
    float sm = 0.f;
    f32x4 o[4];
#pragma unroll
    for (int et = 0; et < 4; ++et) o[et] = (f32x4){0.f, 0.f, 0.f, 0.f};

#pragma unroll
    for (int c = 0; c < 9; ++c) {
        float pv[8];
#pragma unroll
        for (int j = 0; j < 8; ++j) {
            const int t = 2 * c + (j >> 2);
            pv[j] = (t < 17) ? __expf(sc[t][j & 3] - mx) : 0.f;   // masked -> exp(-1e30)=0
            sm += pv[j];
        }
        unsigned int u0 = (unsigned)f2bf(pv[0]) | ((unsigned)f2bf(pv[1]) << 16);
        unsigned int u1 = (unsigned)f2bf(pv[2]) | ((unsigned)f2bf(pv[3]) << 16);
        unsigned int u2 = (unsigned)f2bf(pv[4]) | ((unsigned)f2bf(pv[5]) << 16);
        unsigned int u3 = (unsigned)f2bf(pv[6]) | ((unsigned)f2bf(pv[7]) << 16);
        short* pb = &Pc[wid][c & 1][0];
        *(uint2v*)(pb + fr * PCST + 4 * g)      = (uint2v){u0, u1};  // keys 4g..4g+3 (tile 2c)
        *(uint2v*)(pb + fr * PCST + 16 + 4 * g) = (uint2v){u2, u3};  // keys 16+4g..  (tile 2c+1)
        const short8 pa = *(const short8*)(pb + fr * PCST + 8 * g);  // A-frag: q=fr, k=8g..
        int ka = wid * 16 + 32 * c + 8 * g;
        ka = ka > KWIN - 8 ? KWIN - 8 : ka;        // clamped lanes have P=0
#pragma unroll
        for (int et = 0; et < 4; ++et) {
            const short8 vb = *(const short8*)(Vs + (et * 16 + fr) * VST + ka);
            o[et] = __builtin_amdgcn_mfma_f32_16x16x32_bf16(pa, vb, o[et], 0, 0, 0);
        }
    }

    sm += __shfl_xor(sm, 16);
    sm += __shfl_xor(sm, 32);
    const float inv = 1.0f / sm;                   // valid for query = fr
    float inv4[4];
#pragma unroll
    for (int r = 0; r < 4; ++r) inv4[r] = __shfl(inv, 4 * g + r);   // PV D-row = query 4g+r

#pragma unroll
    for (int et = 0; et < 4; ++et)
#pragma unroll
        for (int r = 0; r < 4; ++r) {
            const int qi = q0 + wid * 16 + 4 * g + r;
            const int dd = hh * HD + et * 16 + fr;
            out[((size_t)qi * NBATCH + bb) * DMODEL + dd] = o[et][r] * inv4[r];
        }
}

extern "C" void kernel_launch(void* const* d_in, const int* in_sizes, int n_in,
                              void* d_out, int out_size, void* d_ws, size_t ws_size,
                              hipStream_t stream) {
    (void)in_sizes; (void)n_in; (void)out_size; (void)ws_size;
    const float* val = (const float*)d_in[0];
    const float* Wq  = (const float*)d_in[1];
    const float* bq  = (const float*)d_in[2];
    const float* Wk  = (const float*)d_in[3];
    const float* bk  = (const float*)d_in[4];
    const float* Wv  = (const float*)d_in[5];
    const float* bv  = (const float*)d_in[6];
    float* out = (float*)d_out;

    char* ws = (char*)d_ws;
    const size_t SZ_X  = (size_t)MROWS * DMODEL * 2;
    const size_t SZ_W  = (size_t)DMODEL * DMODEL * 2;
    short* X  = (short*)(ws);
    short* WT = (short*)(ws + SZ_X);
    short* Qb = (short*)(ws + SZ_X + 3 * SZ_W);
    short* Kb = (short*)(ws + SZ_X + 3 * SZ_W + SZ_X);
    short* Vb = (short*)(ws + SZ_X + 3 * SZ_W + 2 * SZ_X);
    short* Vt = (short*)(ws + SZ_X + 3 * SZ_W + 3 * SZ_X);

    cvt_val_kernel<<<dim3((MROWS * DMODEL) / 4 / 256), dim3(256), 0, stream>>>(val, X);
    cvt_w_kernel<<<dim3(3, 96, 3), dim3(256), 0, stream>>>(Wq, Wk, Wv, WT);
    gemm_qkv_kernel<<<dim3(1152), dim3(256), 0, stream>>>(
        X, WT, bq, bk, bv, Qb, Kb, Vb);
    transpose_v_kernel<<<dim3(NBATCH * NH, S_LEN / 64), dim3(256), 0, stream>>>(Vb, Vt);
    attn_kernel<<<dim3(S_LEN / QB, NBATCH * NH), dim3(512), 0, stream>>>(Qb, Kb, Vt, out);
}